// Round 15
// baseline (341.441 us; speedup 1.0000x reference)
//
#include <hip/hip_runtime.h>

// ProgressiveFocusedAttention, MI355X/gfx950 — fully fused per-window kernel.
// B=4, H=W=128, C=192, 6 heads x 32, window 8x8 (64 tokens), shift 4. 1024 windows.
// Outputs: out (4,128,128,192) fp32 then attn (1024,6,64,64) fp32 (concatenated).
//
// R18: R17 (best, total 322.9us) + zero-pressure L2-warm of each wave's prev tile:
// 4 touch loads (64B lane-stride, 16KB coverage) issued at kernel top, sunk via
// empty asm (no DCE, no held regs). prev lines land in L2 under P0-P3, so P4's
// 64B gathers hit L2 (~200cy) instead of L3/HBM (~450-900cy). Session ledger:
// reorderings regress (R11/R14/R15), zero-pressure additions win (R13/R16/R17)
// — this is the last addition of that class. Everything else = R17 verbatim.
//
// MFMA 16x16x32 bf16 layouts (HW-verified across R0-R17):
//   A[m][k]: m = lane&15, k = (lane>>4)*8 + j
//   B[k][n]: n = lane&15, k = (lane>>4)*8 + j
//   D[r][c]: c = lane&15, r = (lane>>4)*4 + reg
//
// LDS map (shorts), 81,664 total (163,328 B <= 163,840):
//   [0,25600)        xw[win] [64][200] @ win*12800 (persistent, read-only post-P0)
//   [25600,77824)    head region (win*6+h)*4352 @ +25600:
//                      q [64][32] @+0, k [64][32] @+2048 (written in P1 pass epis)
//                      vt [32][72] @+0 (over q, post-QK^T); P-half/o [64][32] @+2304
//   [77824,81664)    lepe stage: 6 heads x 320 f32, shared by both windows
// Barriers (2): P0-end (xw + lepe published), P5-end (o cross-wave publish).

#define SCALE 0.17677669529663687f

typedef __attribute__((ext_vector_type(8))) short short8;
typedef __attribute__((ext_vector_type(4))) float f32x4;

__device__ __forceinline__ unsigned short f2bf(float f) {
    unsigned int u = __float_as_uint(f);
    u = (u + 0x7FFFu + ((u >> 16) & 1u)) >> 16;   // round-to-nearest-even
    return (unsigned short)u;
}
__device__ __forceinline__ float bf2f(unsigned short h) {
    return __uint_as_float(((unsigned int)h) << 16);
}
__device__ __forceinline__ unsigned int pack2(float a, float b) {
    return (unsigned int)f2bf(a) | ((unsigned int)f2bf(b) << 16);
}

// ---------------------------------------------------------------- K0: pack
__global__ __launch_bounds__(256) void k0_pack(const float* __restrict__ qkv_w,
                                               const float* __restrict__ proj_w,
                                               unsigned short* __restrict__ qkvp,
                                               unsigned short* __restrict__ projp) {
    int gid = blockIdx.x * 256 + threadIdx.x;   // grid covers 6*36*64 + 6*12*64 = 18432
    if (gid < 6 * 36 * 64) {
        int lane = gid & 63, tile = gid >> 6;
        int nt = tile % 36, ks = tile / 36;
        int row = ks * 32 + (lane >> 4) * 8, col = nt * 16 + (lane & 15);
        const float* w = qkv_w + (size_t)row * 576 + col;
        uint4 o;
        o.x = pack2(w[0 * 576], w[1 * 576]);
        o.y = pack2(w[2 * 576], w[3 * 576]);
        o.z = pack2(w[4 * 576], w[5 * 576]);
        o.w = pack2(w[6 * 576], w[7 * 576]);
        *(uint4*)(qkvp + (size_t)gid * 8) = o;
    } else {
        int g = gid - 6 * 36 * 64;
        int lane = g & 63, tile = g >> 6;
        int nt = tile % 12, ks = tile / 12;
        int row = ks * 32 + (lane >> 4) * 8, col = nt * 16 + (lane & 15);
        const float* w = proj_w + (size_t)row * 192 + col;
        uint4 o;
        o.x = pack2(w[0 * 192], w[1 * 192]);
        o.y = pack2(w[2 * 192], w[3 * 192]);
        o.z = pack2(w[4 * 192], w[5 * 192]);
        o.w = pack2(w[6 * 192], w[7 * 192]);
        *(uint4*)(projp + (size_t)g * 8) = o;
    }
}

// ---------------------------------------------------------------- fused kernel
#define XWP 12800   // per-window xw region (shorts)
#define HREG 25600  // head regions base (shorts)
#define RH 4352     // per-head region pitch (shorts)
#define KO 2048     // k offset within region
#define PO 2304     // P-half / o offset within region
#define LEPE 77824  // lepe stage base (shorts)

__global__ __launch_bounds__(768, 3) void k_fused(
    const float* __restrict__ x, const float* __restrict__ prev,
    const float* __restrict__ qkv_b, const float* __restrict__ lepe_w,
    const float* __restrict__ lepe_b, const float* __restrict__ proj_b,
    const unsigned short* __restrict__ qkvp, const unsigned short* __restrict__ projp,
    float* __restrict__ out, float* __restrict__ attn)
{
    __shared__ unsigned short lds[81664];   // 163,328 B (<= 160 KiB)
    const int t = threadIdx.x;
    const int win = (t >= 384) ? 1 : 0;
    const int tl = t - win * 384;              // thread id within the window half
    const int wb = blockIdx.x * 2 + win;
    const int b = wb >> 8, wh = (wb >> 4) & 15, wwi = wb & 15;
    const int lane = tl & 63, h = tl >> 6, quad = lane >> 4, l16 = lane & 15;
    unsigned short* xww = &lds[win * XWP];     // this window's xw [64][200]
    const f32x4 fz = {0.f, 0.f, 0.f, 0.f};

    // L2-warm touch of this wave's prev tile (16 KB): 4 loads at 64B lane-stride,
    // issued first (oldest in vmcnt queue, complete under P0-P3), results sunk.
    const float* pvm = prev + (((size_t)wb * 6 + h) << 12);
    {
        const float* pt = pvm + lane * 16;     // 64 lanes x 64B = 4KB per instr
        float t0 = pt[0], t1 = pt[1024], t2 = pt[2048], t3 = pt[3072];
        asm volatile("" :: "v"(t0), "v"(t1), "v"(t2), "v"(t3));
    }

    // Stage head h's LePE weights (9 taps x 32 ch, tap-major) + bias — ONE shared
    // copy for both windows; win0's wave writes it before the P0-end barrier.
    float* lw = (float*)&lds[LEPE] + h * 320;
    if (win == 0) {
        for (int i = lane; i < 320; i += 64) {
            float v = (i < 288) ? lepe_w[(i >> 5) * 192 + h * 32 + (i & 31)]
                                : lepe_b[h * 32 + (i - 288)];
            lw[i] = v;
        }
    }

    // ---- P0: shifted-window load, fp32 -> bf16, coalesced; xw [64][200]
#pragma unroll
    for (int kk = 0; kk < 8; ++kk) {
        int f = kk * 384 + tl;                 // float4 id within window, 0..3071
        int token = f / 48, c4 = f - token * 48;
        int i = token >> 3, j = token & 7;
        int hh = (wh * 8 + i + 4) & 127, wp = (wwi * 8 + j + 4) & 127;
        const float4 v4 = *(const float4*)(x + ((size_t)((b * 128 + hh) * 128 + wp)) * 192 + c4 * 4);
        unsigned int* d = (unsigned int*)&xww[token * 200 + c4 * 4];
        d[0] = pack2(v4.x, v4.y);
        d[1] = pack2(v4.z, v4.w);
    }
    __syncthreads();   // P0-end: xw + lepe stage published. (Barrier 1 of 2.)

    // column-tile ids for this head: q:{2h,2h+1} k:{12+2h,13+2h} v:{24+2h,25+2h}
    const int ntg[6] = {2 * h, 2 * h + 1, 12 + 2 * h, 13 + 2 * h, 24 + 2 * h, 25 + 2 * h};
    unsigned short* qh  = &lds[HREG + (win * 6 + h) * RH];
    unsigned short* kh  = qh + KO;
    unsigned short* vth = qh;          // vt [32][72] overlays q (+ dead k head) post-QK^T
    unsigned short* Pf  = qh + PO;     // P-half / o region

    // ---- P1: qkv_h = xw(64x192) @ W[:, head-h tiles]; three passes (Q,K,V).
    // xw is NOT aliased -> q/k store straight to LDS in their pass epilogues
    // (wave-private region, no barrier); v stays packed in regs until post-QK^T.
    unsigned int vpk[4][4];

#pragma unroll
    for (int pass = 0; pass < 3; ++pass) {
        f32x4 a2[2][4];
#pragma unroll
        for (int jj = 0; jj < 2; ++jj)
#pragma unroll
            for (int m = 0; m < 4; ++m) a2[jj][m] = fz;

#pragma unroll
        for (int ks = 0; ks < 6; ++ks) {
            short8 a[4];
#pragma unroll
            for (int m = 0; m < 4; ++m)
                a[m] = *(const short8*)&xww[(m * 16 + l16) * 200 + ks * 32 + quad * 8];
            __builtin_amdgcn_s_setprio(1);   // T5: favor this wave through the MFMA cluster
#pragma unroll
            for (int jj = 0; jj < 2; ++jj) {
                short8 bf = *(const short8*)(qkvp +
                    (((size_t)(ks * 36 + ntg[pass * 2 + jj]) * 64 + lane) << 3));
#pragma unroll
                for (int m = 0; m < 4; ++m)
                    a2[jj][m] = __builtin_amdgcn_mfma_f32_16x16x32_bf16(a[m], bf, a2[jj][m], 0, 0, 0);
            }
            __builtin_amdgcn_s_setprio(0);
        }
        float b0 = qkv_b[ntg[pass * 2] * 16 + l16];
        float b1 = qkv_b[ntg[pass * 2 + 1] * 16 + l16];
        if (pass < 2) {
            unsigned short* base = (pass == 0) ? qh : kh;
#pragma unroll
            for (int m = 0; m < 4; ++m)
#pragma unroll
                for (int r = 0; r < 4; ++r) {
                    int token = m * 16 + quad * 4 + r;
                    base[token * 32 + l16]      = f2bf(a2[0][m][r] + b0);
                    base[token * 32 + 16 + l16] = f2bf(a2[1][m][r] + b1);
                }
        } else {
#pragma unroll
            for (int m = 0; m < 4; ++m)
#pragma unroll
                for (int r = 0; r < 4; ++r)
                    vpk[m][r] = pack2(a2[0][m][r] + b0, a2[1][m][r] + b1);
        }
    }
    // No barrier: q/k/vt/Pf are wave-private until the P5-end barrier.

    // ---- P3: QK^T (whole head per wave: 4x4 tiles, K=32 in one MFMA step)
    f32x4 s4[4][4];
    {
        short8 aq[4];
#pragma unroll
        for (int m = 0; m < 4; ++m)
            aq[m] = *(const short8*)(qh + (m * 16 + l16) * 32 + quad * 8);
        __builtin_amdgcn_s_setprio(1);       // T5
#pragma unroll
        for (int nt = 0; nt < 4; ++nt) {
            short8 bk = *(const short8*)(kh + (nt * 16 + l16) * 32 + quad * 8);
#pragma unroll
            for (int m = 0; m < 4; ++m)
                s4[m][nt] = __builtin_amdgcn_mfma_f32_16x16x32_bf16(aq[m], bk, fz, 0, 0, 0);
        }
        __builtin_amdgcn_s_setprio(0);
    }

    // ---- vt write over dead q strip (k head tail dead too): layout [ch][token]
#pragma unroll
    for (int m = 0; m < 4; ++m)
#pragma unroll
        for (int r = 0; r < 4; ++r) {
            int token = m * 16 + quad * 4 + r;
            unsigned int uv = vpk[m][r];
            vth[l16 * 72 + token]        = (unsigned short)(uv & 0xFFFFu);
            vth[(16 + l16) * 72 + token] = (unsigned short)(uv >> 16);
        }

    // ---- P2: LePE 3x3 depthwise conv (zero-pad inside window) + residual, in place.
    // Channels independent; all 9 reads of channel ci precede its write (proven).
    // Weights/bias from the shared LDS stage (broadcast reads, conflict-free).
    {
        const int ti = lane >> 3, tj = lane & 7;
#pragma unroll 8
        for (int ci = 0; ci < 32; ++ci) {
            const unsigned short* vr = vth + ci * 72;
            float sum = bf2f(vr[lane]) + lw[288 + ci];
#pragma unroll
            for (int di = -1; di <= 1; ++di)
#pragma unroll
                for (int dj = -1; dj <= 1; ++dj) {
                    int ii = ti + di, jj = tj + dj;
                    if (ii >= 0 && ii < 8 && jj >= 0 && jj < 8)
                        sum += bf2f(vr[ii * 8 + jj]) * lw[((di + 1) * 3 + (dj + 1)) * 32 + ci];
                }
            vth[ci * 72 + lane] = f2bf(sum);
        }
    }

    // ---- P4: gate with prev, softmax (fp32, |scores| small: no max-sub), write attn;
    // keep P values in s4 for the two-half PV. (R13/R16 path verbatim — the
    // interleaved store schedule is load-bearing, R14/R15.)
    float* aom = attn + (((size_t)wb * 6 + h) << 12);
#pragma unroll
    for (int m = 0; m < 4; ++m) {
        float inv[4];
#pragma unroll
        for (int r = 0; r < 4; ++r) {
            int row = m * 16 + quad * 4 + r;
            float ps = 0.f;
#pragma unroll
            for (int nt = 0; nt < 4; ++nt) {
                float sg = s4[m][nt][r] * SCALE * pvm[row * 64 + nt * 16 + l16];
                float ev = __expf(sg);
                s4[m][nt][r] = ev; ps += ev;
            }
            ps += __shfl_xor(ps, 1); ps += __shfl_xor(ps, 2);
            ps += __shfl_xor(ps, 4); ps += __shfl_xor(ps, 8);
            inv[r] = 1.0f / ps;
        }
#pragma unroll
        for (int r = 0; r < 4; ++r) {
            int row = m * 16 + quad * 4 + r;
#pragma unroll
            for (int nt = 0; nt < 4; ++nt) {
                float av = s4[m][nt][r] * inv[r];
                s4[m][nt][r] = av;
                aom[row * 64 + nt * 16 + l16] = av;
            }
        }
    }

    // ---- P5: PV in two K=32 halves; P-half [64][32] @ Pf, consumed immediately
    {
        f32x4 o2[4][2];
#pragma unroll
        for (int m = 0; m < 4; ++m) { o2[m][0] = fz; o2[m][1] = fz; }
#pragma unroll
        for (int half = 0; half < 2; ++half) {
            // store this half of P (keys half*32 .. half*32+31)
#pragma unroll
            for (int m = 0; m < 4; ++m)
#pragma unroll
                for (int nt2 = 0; nt2 < 2; ++nt2)
#pragma unroll
                    for (int r = 0; r < 4; ++r) {
                        int row = m * 16 + quad * 4 + r;
                        Pf[row * 32 + nt2 * 16 + l16] = f2bf(s4[m][half * 2 + nt2][r]);
                    }
            // consume: O += P_half @ V_half
            short8 ap[4];
#pragma unroll
            for (int m = 0; m < 4; ++m)
                ap[m] = *(const short8*)(Pf + (m * 16 + l16) * 32 + quad * 8);
            __builtin_amdgcn_s_setprio(1);   // T5
#pragma unroll
            for (int n2 = 0; n2 < 2; ++n2) {
                short8 bv = *(const short8*)(vth + (n2 * 16 + l16) * 72 + half * 32 + quad * 8);
#pragma unroll
                for (int m = 0; m < 4; ++m)
                    o2[m][n2] = __builtin_amdgcn_mfma_f32_16x16x32_bf16(ap[m], bv, o2[m][n2], 0, 0, 0);
            }
            __builtin_amdgcn_s_setprio(0);
        }
        // o_h [64][32] over the consumed P-half region
#pragma unroll
        for (int m = 0; m < 4; ++m)
#pragma unroll
            for (int n2 = 0; n2 < 2; ++n2)
#pragma unroll
                for (int r = 0; r < 4; ++r) {
                    int token = m * 16 + quad * 4 + r;
                    Pf[token * 32 + n2 * 16 + l16] = f2bf(o2[m][n2][r]);
                }
    }
    __syncthreads();   // P5-end: all heads' o_h staged. (Barrier 2 of 2.)

    // ---- P6: proj: out(64x192) = o(64x192) @ proj_w; wave h owns 2 N-tiles.
    {
        f32x4 p3[2][4];
#pragma unroll
        for (int n = 0; n < 2; ++n)
#pragma unroll
            for (int m = 0; m < 4; ++m) p3[n][m] = fz;

#pragma unroll
        for (int ks = 0; ks < 6; ++ks) {
            const unsigned short* ob = &lds[HREG + (win * 6 + ks) * RH + PO];  // head-ks o [64][32]
            short8 a3[4];
#pragma unroll
            for (int m = 0; m < 4; ++m)
                a3[m] = *(const short8*)(ob + (m * 16 + l16) * 32 + quad * 8);
            __builtin_amdgcn_s_setprio(1);   // T5
#pragma unroll
            for (int n = 0; n < 2; ++n) {
                short8 bf = *(const short8*)(projp + (((size_t)(ks * 12 + h * 2 + n) * 64 + lane) << 3));
#pragma unroll
                for (int m = 0; m < 4; ++m)
                    p3[n][m] = __builtin_amdgcn_mfma_f32_16x16x32_bf16(a3[m], bf, p3[n][m], 0, 0, 0);
            }
            __builtin_amdgcn_s_setprio(0);
        }
#pragma unroll
        for (int n = 0; n < 2; ++n) {
            int col = (h * 2 + n) * 16 + l16;
            float bias = proj_b[col];
#pragma unroll
            for (int m = 0; m < 4; ++m)
#pragma unroll
                for (int r = 0; r < 4; ++r) {
                    int token = m * 16 + quad * 4 + r;
                    int i = token >> 3, j = token & 7;
                    int hh = (wh * 8 + i + 4) & 127, wp = (wwi * 8 + j + 4) & 127;
                    out[((size_t)((b * 128 + hh) * 128 + wp)) * 192 + col] = p3[n][m][r] + bias;
                }
        }
    }
}

// ---------------------------------------------------------------- launch
extern "C" void kernel_launch(void* const* d_in, const int* in_sizes, int n_in,
                              void* d_out, int out_size, void* d_ws, size_t ws_size,
                              hipStream_t stream) {
    const float* x      = (const float*)d_in[0];
    const float* prev   = (const float*)d_in[1];
    const float* qkv_w  = (const float*)d_in[2];
    const float* qkv_b  = (const float*)d_in[3];
    const float* proj_w = (const float*)d_in[4];
    const float* proj_b = (const float*)d_in[5];
    const float* lepe_w = (const float*)d_in[6];
    const float* lepe_b = (const float*)d_in[7];

    float* out  = (float*)d_out;
    float* attn = out + (size_t)4 * 128 * 128 * 192;   // second output, concatenated

    char* ws = (char*)d_ws;
    const size_t SZ_QKVP = 192 * 576 * 2;              // 221184
    unsigned short* qkvp  = (unsigned short*)(ws);
    unsigned short* projp = (unsigned short*)(ws + SZ_QKVP);

    k0_pack<<<72, 256, 0, stream>>>(qkv_w, proj_w, qkvp, projp);
    k_fused<<<512, 768, 0, stream>>>(x, prev, qkv_b, lepe_w, lepe_b, proj_b,
                                     qkvp, projp, out, attn);
}

// Round 16
// 320.385 us; speedup vs baseline: 1.0657x; 1.0657x over previous
//
#include <hip/hip_runtime.h>

// ProgressiveFocusedAttention, MI355X/gfx950 — fully fused per-window kernel.
// B=4, H=W=128, C=192, 6 heads x 32, window 8x8 (64 tokens), shift 4. 1024 windows.
// Outputs: out (4,128,128,192) fp32 then attn (1024,6,64,64) fp32 (concatenated).
//
// R19 = R17 verbatim (session best: 322.9us total). R18's prev L2-warm touch
// regressed (341us): the 4 touch loads sat oldest in vmcnt at the kernel's
// critical front edge, and 12 co-resident 16KB tiles x 32 CUs/XCD = 6MB > 4MB L2
// partially evicted before P4 consumed them. P4-prev-latency is triple-
// disconfirmed (R11 spill / R12 neutral / R18 regression).
//
// Session ledger (421 -> 322.9us):
//   WINS (zero-pressure, dependency-loosening): full fusion (R5), 2-window/768t
//   WG (R10, 12 waves/CU), conv weight LDS staging (R13), T5 setprio (R16),
//   xw un-alias -> 2-barrier (R17).
//   LOSSES (reorderings / front-edge traffic): R11, R14, R15, R18.
//   CEILINGS: 12 waves/CU (unified-register cap for MFMA-bearing 768t blocks);
//   ~186us fixed harness overhead; compiler schedule of the wave-private chain
//   is load-bearing as written.
//
// MFMA 16x16x32 bf16 layouts (HW-verified across R0-R18):
//   A[m][k]: m = lane&15, k = (lane>>4)*8 + j
//   B[k][n]: n = lane&15, k = (lane>>4)*8 + j
//   D[r][c]: c = lane&15, r = (lane>>4)*4 + reg
//
// LDS map (shorts), 81,664 total (163,328 B <= 163,840):
//   [0,25600)        xw[win] [64][200] @ win*12800 (persistent, read-only post-P0)
//   [25600,77824)    head region (win*6+h)*4352 @ +25600:
//                      q [64][32] @+0, k [64][32] @+2048 (written in P1 pass epis)
//                      vt [32][72] @+0 (over q, post-QK^T); P-half/o [64][32] @+2304
//   [77824,81664)    lepe stage: 6 heads x 320 f32, shared by both windows
// Barriers (2): P0-end (xw + lepe published), P5-end (o cross-wave publish).

#define SCALE 0.17677669529663687f

typedef __attribute__((ext_vector_type(8))) short short8;
typedef __attribute__((ext_vector_type(4))) float f32x4;

__device__ __forceinline__ unsigned short f2bf(float f) {
    unsigned int u = __float_as_uint(f);
    u = (u + 0x7FFFu + ((u >> 16) & 1u)) >> 16;   // round-to-nearest-even
    return (unsigned short)u;
}
__device__ __forceinline__ float bf2f(unsigned short h) {
    return __uint_as_float(((unsigned int)h) << 16);
}
__device__ __forceinline__ unsigned int pack2(float a, float b) {
    return (unsigned int)f2bf(a) | ((unsigned int)f2bf(b) << 16);
}

// ---------------------------------------------------------------- K0: pack
__global__ __launch_bounds__(256) void k0_pack(const float* __restrict__ qkv_w,
                                               const float* __restrict__ proj_w,
                                               unsigned short* __restrict__ qkvp,
                                               unsigned short* __restrict__ projp) {
    int gid = blockIdx.x * 256 + threadIdx.x;   // grid covers 6*36*64 + 6*12*64 = 18432
    if (gid < 6 * 36 * 64) {
        int lane = gid & 63, tile = gid >> 6;
        int nt = tile % 36, ks = tile / 36;
        int row = ks * 32 + (lane >> 4) * 8, col = nt * 16 + (lane & 15);
        const float* w = qkv_w + (size_t)row * 576 + col;
        uint4 o;
        o.x = pack2(w[0 * 576], w[1 * 576]);
        o.y = pack2(w[2 * 576], w[3 * 576]);
        o.z = pack2(w[4 * 576], w[5 * 576]);
        o.w = pack2(w[6 * 576], w[7 * 576]);
        *(uint4*)(qkvp + (size_t)gid * 8) = o;
    } else {
        int g = gid - 6 * 36 * 64;
        int lane = g & 63, tile = g >> 6;
        int nt = tile % 12, ks = tile / 12;
        int row = ks * 32 + (lane >> 4) * 8, col = nt * 16 + (lane & 15);
        const float* w = proj_w + (size_t)row * 192 + col;
        uint4 o;
        o.x = pack2(w[0 * 192], w[1 * 192]);
        o.y = pack2(w[2 * 192], w[3 * 192]);
        o.z = pack2(w[4 * 192], w[5 * 192]);
        o.w = pack2(w[6 * 192], w[7 * 192]);
        *(uint4*)(projp + (size_t)g * 8) = o;
    }
}

// ---------------------------------------------------------------- fused kernel
#define XWP 12800   // per-window xw region (shorts)
#define HREG 25600  // head regions base (shorts)
#define RH 4352     // per-head region pitch (shorts)
#define KO 2048     // k offset within region
#define PO 2304     // P-half / o offset within region
#define LEPE 77824  // lepe stage base (shorts)

__global__ __launch_bounds__(768, 3) void k_fused(
    const float* __restrict__ x, const float* __restrict__ prev,
    const float* __restrict__ qkv_b, const float* __restrict__ lepe_w,
    const float* __restrict__ lepe_b, const float* __restrict__ proj_b,
    const unsigned short* __restrict__ qkvp, const unsigned short* __restrict__ projp,
    float* __restrict__ out, float* __restrict__ attn)
{
    __shared__ unsigned short lds[81664];   // 163,328 B (<= 160 KiB)
    const int t = threadIdx.x;
    const int win = (t >= 384) ? 1 : 0;
    const int tl = t - win * 384;              // thread id within the window half
    const int wb = blockIdx.x * 2 + win;
    const int b = wb >> 8, wh = (wb >> 4) & 15, wwi = wb & 15;
    const int lane = tl & 63, h = tl >> 6, quad = lane >> 4, l16 = lane & 15;
    unsigned short* xww = &lds[win * XWP];     // this window's xw [64][200]
    const f32x4 fz = {0.f, 0.f, 0.f, 0.f};

    // Stage head h's LePE weights (9 taps x 32 ch, tap-major) + bias — ONE shared
    // copy for both windows; win0's wave writes it before the P0-end barrier.
    float* lw = (float*)&lds[LEPE] + h * 320;
    if (win == 0) {
        for (int i = lane; i < 320; i += 64) {
            float v = (i < 288) ? lepe_w[(i >> 5) * 192 + h * 32 + (i & 31)]
                                : lepe_b[h * 32 + (i - 288)];
            lw[i] = v;
        }
    }

    // ---- P0: shifted-window load, fp32 -> bf16, coalesced; xw [64][200]
#pragma unroll
    for (int kk = 0; kk < 8; ++kk) {
        int f = kk * 384 + tl;                 // float4 id within window, 0..3071
        int token = f / 48, c4 = f - token * 48;
        int i = token >> 3, j = token & 7;
        int hh = (wh * 8 + i + 4) & 127, wp = (wwi * 8 + j + 4) & 127;
        const float4 v4 = *(const float4*)(x + ((size_t)((b * 128 + hh) * 128 + wp)) * 192 + c4 * 4);
        unsigned int* d = (unsigned int*)&xww[token * 200 + c4 * 4];
        d[0] = pack2(v4.x, v4.y);
        d[1] = pack2(v4.z, v4.w);
    }
    __syncthreads();   // P0-end: xw + lepe stage published. (Barrier 1 of 2.)

    // column-tile ids for this head: q:{2h,2h+1} k:{12+2h,13+2h} v:{24+2h,25+2h}
    const int ntg[6] = {2 * h, 2 * h + 1, 12 + 2 * h, 13 + 2 * h, 24 + 2 * h, 25 + 2 * h};
    unsigned short* qh  = &lds[HREG + (win * 6 + h) * RH];
    unsigned short* kh  = qh + KO;
    unsigned short* vth = qh;          // vt [32][72] overlays q (+ dead k head) post-QK^T
    unsigned short* Pf  = qh + PO;     // P-half / o region

    // ---- P1: qkv_h = xw(64x192) @ W[:, head-h tiles]; three passes (Q,K,V).
    // xw is NOT aliased -> q/k store straight to LDS in their pass epilogues
    // (wave-private region, no barrier); v stays packed in regs until post-QK^T.
    unsigned int vpk[4][4];

#pragma unroll
    for (int pass = 0; pass < 3; ++pass) {
        f32x4 a2[2][4];
#pragma unroll
        for (int jj = 0; jj < 2; ++jj)
#pragma unroll
            for (int m = 0; m < 4; ++m) a2[jj][m] = fz;

#pragma unroll
        for (int ks = 0; ks < 6; ++ks) {
            short8 a[4];
#pragma unroll
            for (int m = 0; m < 4; ++m)
                a[m] = *(const short8*)&xww[(m * 16 + l16) * 200 + ks * 32 + quad * 8];
            __builtin_amdgcn_s_setprio(1);   // T5: favor this wave through the MFMA cluster
#pragma unroll
            for (int jj = 0; jj < 2; ++jj) {
                short8 bf = *(const short8*)(qkvp +
                    (((size_t)(ks * 36 + ntg[pass * 2 + jj]) * 64 + lane) << 3));
#pragma unroll
                for (int m = 0; m < 4; ++m)
                    a2[jj][m] = __builtin_amdgcn_mfma_f32_16x16x32_bf16(a[m], bf, a2[jj][m], 0, 0, 0);
            }
            __builtin_amdgcn_s_setprio(0);
        }
        float b0 = qkv_b[ntg[pass * 2] * 16 + l16];
        float b1 = qkv_b[ntg[pass * 2 + 1] * 16 + l16];
        if (pass < 2) {
            unsigned short* base = (pass == 0) ? qh : kh;
#pragma unroll
            for (int m = 0; m < 4; ++m)
#pragma unroll
                for (int r = 0; r < 4; ++r) {
                    int token = m * 16 + quad * 4 + r;
                    base[token * 32 + l16]      = f2bf(a2[0][m][r] + b0);
                    base[token * 32 + 16 + l16] = f2bf(a2[1][m][r] + b1);
                }
        } else {
#pragma unroll
            for (int m = 0; m < 4; ++m)
#pragma unroll
                for (int r = 0; r < 4; ++r)
                    vpk[m][r] = pack2(a2[0][m][r] + b0, a2[1][m][r] + b1);
        }
    }
    // No barrier: q/k/vt/Pf are wave-private until the P5-end barrier.

    // ---- P3: QK^T (whole head per wave: 4x4 tiles, K=32 in one MFMA step)
    f32x4 s4[4][4];
    {
        short8 aq[4];
#pragma unroll
        for (int m = 0; m < 4; ++m)
            aq[m] = *(const short8*)(qh + (m * 16 + l16) * 32 + quad * 8);
        __builtin_amdgcn_s_setprio(1);       // T5
#pragma unroll
        for (int nt = 0; nt < 4; ++nt) {
            short8 bk = *(const short8*)(kh + (nt * 16 + l16) * 32 + quad * 8);
#pragma unroll
            for (int m = 0; m < 4; ++m)
                s4[m][nt] = __builtin_amdgcn_mfma_f32_16x16x32_bf16(aq[m], bk, fz, 0, 0, 0);
        }
        __builtin_amdgcn_s_setprio(0);
    }

    // ---- vt write over dead q strip (k head tail dead too): layout [ch][token]
#pragma unroll
    for (int m = 0; m < 4; ++m)
#pragma unroll
        for (int r = 0; r < 4; ++r) {
            int token = m * 16 + quad * 4 + r;
            unsigned int uv = vpk[m][r];
            vth[l16 * 72 + token]        = (unsigned short)(uv & 0xFFFFu);
            vth[(16 + l16) * 72 + token] = (unsigned short)(uv >> 16);
        }

    // ---- P2: LePE 3x3 depthwise conv (zero-pad inside window) + residual, in place.
    // Channels independent; all 9 reads of channel ci precede its write (proven).
    // Weights/bias from the shared LDS stage (broadcast reads, conflict-free).
    {
        const int ti = lane >> 3, tj = lane & 7;
#pragma unroll 8
        for (int ci = 0; ci < 32; ++ci) {
            const unsigned short* vr = vth + ci * 72;
            float sum = bf2f(vr[lane]) + lw[288 + ci];
#pragma unroll
            for (int di = -1; di <= 1; ++di)
#pragma unroll
                for (int dj = -1; dj <= 1; ++dj) {
                    int ii = ti + di, jj = tj + dj;
                    if (ii >= 0 && ii < 8 && jj >= 0 && jj < 8)
                        sum += bf2f(vr[ii * 8 + jj]) * lw[((di + 1) * 3 + (dj + 1)) * 32 + ci];
                }
            vth[ci * 72 + lane] = f2bf(sum);
        }
    }

    // ---- P4: gate with prev, softmax (fp32, |scores| small: no max-sub), write attn;
    // keep P values in s4 for the two-half PV. (R13/R16 path verbatim — the
    // interleaved store schedule is load-bearing, R14/R15.)
    const float* pvm = prev + (((size_t)wb * 6 + h) << 12);
    float* aom = attn + (((size_t)wb * 6 + h) << 12);
#pragma unroll
    for (int m = 0; m < 4; ++m) {
        float inv[4];
#pragma unroll
        for (int r = 0; r < 4; ++r) {
            int row = m * 16 + quad * 4 + r;
            float ps = 0.f;
#pragma unroll
            for (int nt = 0; nt < 4; ++nt) {
                float sg = s4[m][nt][r] * SCALE * pvm[row * 64 + nt * 16 + l16];
                float ev = __expf(sg);
                s4[m][nt][r] = ev; ps += ev;
            }
            ps += __shfl_xor(ps, 1); ps += __shfl_xor(ps, 2);
            ps += __shfl_xor(ps, 4); ps += __shfl_xor(ps, 8);
            inv[r] = 1.0f / ps;
        }
#pragma unroll
        for (int r = 0; r < 4; ++r) {
            int row = m * 16 + quad * 4 + r;
#pragma unroll
            for (int nt = 0; nt < 4; ++nt) {
                float av = s4[m][nt][r] * inv[r];
                s4[m][nt][r] = av;
                aom[row * 64 + nt * 16 + l16] = av;
            }
        }
    }

    // ---- P5: PV in two K=32 halves; P-half [64][32] @ Pf, consumed immediately
    {
        f32x4 o2[4][2];
#pragma unroll
        for (int m = 0; m < 4; ++m) { o2[m][0] = fz; o2[m][1] = fz; }
#pragma unroll
        for (int half = 0; half < 2; ++half) {
            // store this half of P (keys half*32 .. half*32+31)
#pragma unroll
            for (int m = 0; m < 4; ++m)
#pragma unroll
                for (int nt2 = 0; nt2 < 2; ++nt2)
#pragma unroll
                    for (int r = 0; r < 4; ++r) {
                        int row = m * 16 + quad * 4 + r;
                        Pf[row * 32 + nt2 * 16 + l16] = f2bf(s4[m][half * 2 + nt2][r]);
                    }
            // consume: O += P_half @ V_half
            short8 ap[4];
#pragma unroll
            for (int m = 0; m < 4; ++m)
                ap[m] = *(const short8*)(Pf + (m * 16 + l16) * 32 + quad * 8);
            __builtin_amdgcn_s_setprio(1);   // T5
#pragma unroll
            for (int n2 = 0; n2 < 2; ++n2) {
                short8 bv = *(const short8*)(vth + (n2 * 16 + l16) * 72 + half * 32 + quad * 8);
#pragma unroll
                for (int m = 0; m < 4; ++m)
                    o2[m][n2] = __builtin_amdgcn_mfma_f32_16x16x32_bf16(ap[m], bv, o2[m][n2], 0, 0, 0);
            }
            __builtin_amdgcn_s_setprio(0);
        }
        // o_h [64][32] over the consumed P-half region
#pragma unroll
        for (int m = 0; m < 4; ++m)
#pragma unroll
            for (int n2 = 0; n2 < 2; ++n2)
#pragma unroll
                for (int r = 0; r < 4; ++r) {
                    int token = m * 16 + quad * 4 + r;
                    Pf[token * 32 + n2 * 16 + l16] = f2bf(o2[m][n2][r]);
                }
    }
    __syncthreads();   // P5-end: all heads' o_h staged. (Barrier 2 of 2.)

    // ---- P6: proj: out(64x192) = o(64x192) @ proj_w; wave h owns 2 N-tiles.
    {
        f32x4 p3[2][4];
#pragma unroll
        for (int n = 0; n < 2; ++n)
#pragma unroll
            for (int m = 0; m < 4; ++m) p3[n][m] = fz;

#pragma unroll
        for (int ks = 0; ks < 6; ++ks) {
            const unsigned short* ob = &lds[HREG + (win * 6 + ks) * RH + PO];  // head-ks o [64][32]
            short8 a3[4];
#pragma unroll
            for (int m = 0; m < 4; ++m)
                a3[m] = *(const short8*)(ob + (m * 16 + l16) * 32 + quad * 8);
            __builtin_amdgcn_s_setprio(1);   // T5
#pragma unroll
            for (int n = 0; n < 2; ++n) {
                short8 bf = *(const short8*)(projp + (((size_t)(ks * 12 + h * 2 + n) * 64 + lane) << 3));
#pragma unroll
                for (int m = 0; m < 4; ++m)
                    p3[n][m] = __builtin_amdgcn_mfma_f32_16x16x32_bf16(a3[m], bf, p3[n][m], 0, 0, 0);
            }
            __builtin_amdgcn_s_setprio(0);
        }
#pragma unroll
        for (int n = 0; n < 2; ++n) {
            int col = (h * 2 + n) * 16 + l16;
            float bias = proj_b[col];
#pragma unroll
            for (int m = 0; m < 4; ++m)
#pragma unroll
                for (int r = 0; r < 4; ++r) {
                    int token = m * 16 + quad * 4 + r;
                    int i = token >> 3, j = token & 7;
                    int hh = (wh * 8 + i + 4) & 127, wp = (wwi * 8 + j + 4) & 127;
                    out[((size_t)((b * 128 + hh) * 128 + wp)) * 192 + col] = p3[n][m][r] + bias;
                }
        }
    }
}

// ---------------------------------------------------------------- launch
extern "C" void kernel_launch(void* const* d_in, const int* in_sizes, int n_in,
                              void* d_out, int out_size, void* d_ws, size_t ws_size,
                              hipStream_t stream) {
    const float* x      = (const float*)d_in[0];
    const float* prev   = (const float*)d_in[1];
    const float* qkv_w  = (const float*)d_in[2];
    const float* qkv_b  = (const float*)d_in[3];
    const float* proj_w = (const float*)d_in[4];
    const float* proj_b = (const float*)d_in[5];
    const float* lepe_w = (const float*)d_in[6];
    const float* lepe_b = (const float*)d_in[7];

    float* out  = (float*)d_out;
    float* attn = out + (size_t)4 * 128 * 128 * 192;   // second output, concatenated

    char* ws = (char*)d_ws;
    const size_t SZ_QKVP = 192 * 576 * 2;              // 221184
    unsigned short* qkvp  = (unsigned short*)(ws);
    unsigned short* projp = (unsigned short*)(ws + SZ_QKVP);

    k0_pack<<<72, 256, 0, stream>>>(qkv_w, proj_w, qkvp, projp);
    k_fused<<<512, 768, 0, stream>>>(x, prev, qkv_b, lepe_w, lepe_b, proj_b,
                                     qkvp, projp, out, attn);
}